// Round 1
// baseline (132.209 us; speedup 1.0000x reference)
//
#include <hip/hip_runtime.h>
#include <math.h>

#ifndef M_PI
#define M_PI 3.14159265358979323846
#endif

#define DMODEL 256
#define NSTATE 64
#define LSEQ   8192
#define INVL   (1.0f/8192.0f)

// Workspace layout (bytes).
#define OFF_TW  0                                  // float2[6144]: e^{+2pi i j/L}, j<3L/4
#define OFF_DN  (6144*8)                           // float4[2*DMODEL*NSTATE]
#define OFF_CDT (OFF_DN + DMODEL*NSTATE*32)        // float[DMODEL]: 2/dt
#define OFF_KH  (OFF_CDT + 1024)                   // float4[DMODEL*4096]: K_hat pairs (16 MB)
#define WS_NEED ((size_t)OFF_KH + (size_t)DMODEL*4096*16)

__device__ __forceinline__ float sin_rev(float r) {
#if __has_builtin(__builtin_amdgcn_sinf)
  return __builtin_amdgcn_sinf(r);        // D = sin(S0 * 2pi), input in revolutions
#else
  return __sinf(r * 6.283185307179586f);
#endif
}
__device__ __forceinline__ float cos_rev(float r) {
#if __has_builtin(__builtin_amdgcn_cosf)
  return __builtin_amdgcn_cosf(r);
#else
  return __cosf(r * 6.283185307179586f);
#endif
}

__device__ __forceinline__ float2 cmul(float2 a, float2 b) {
  return make_float2(a.x*b.x - a.y*b.y, a.x*b.y + a.y*b.x);
}

// K_hat/L from the 4 complex sums. PRB*BRP = (S1+iS2)(S1-iS2) = S1^2 + S2^2.
// Prefactor 2/(1+z) = 1 + i*T; fold 1/L here.
__device__ __forceinline__ float2 woodbury(float2 S1, float2 S2, float2 S3,
                                           float2 S4, float T) {
  float nr = (S1.x*S1.x - S1.y*S1.y) + (S2.x*S2.x - S2.y*S2.y);
  float ni = 2.0f*(S1.x*S1.y + S2.x*S2.y);
  float dr = 1.0f + S3.x, di = S3.y;
  float inv = __builtin_amdgcn_rcpf(fmaf(dr, dr, di*di));
  float qr = (nr*dr + ni*di) * inv;
  float qi = (ni*dr - nr*di) * inv;
  float vr = S4.x - qr, vi = S4.y - qi;
  return make_float2((vr - T*vi)*INVL, (vi + T*vr)*INVL);
}

// ---------------------------------------------------------------- precompute
__global__ __launch_bounds__(256) void precompute_kernel(
    const float* __restrict__ Lre, const float* __restrict__ Lim,
    const float* __restrict__ Pre, const float* __restrict__ Pim,
    const float* __restrict__ Bre, const float* __restrict__ Bim,
    const float* __restrict__ log_dt, char* __restrict__ ws)
{
  const int t = blockIdx.x * blockDim.x + threadIdx.x;  // 0..16383
  float2* tw  = (float2*)(ws + OFF_TW);
  float4* dn  = (float4*)(ws + OFF_DN);
  float*  cdt = (float*)(ws + OFF_CDT);

  if (t < 6144) {
    double th = (2.0 * M_PI / (double)LSEQ) * (double)t;
    double s, c; sincos(th, &s, &c);
    tw[t] = make_float2((float)c, (float)s);
  }
  {
    float lre = Lre[t], lim = Lim[t];
    float pre = Pre[t], pim = Pim[t];
    float bre = Bre[t], bim = Bim[t];
    float sp = fmaxf(lre, 0.0f) + log1pf(expf(-fabsf(lre)));  // softplus
    float w1r = pre*bre + pim*bim;   // Re conj(P)*B
    float w1i = pre*bim - pim*bre;   // Im conj(P)*B
    float w2  = pre*pre + pim*pim;   // |P|^2
    float w3  = bre*bre + bim*bim;   // |B|^2
    dn[2*t]   = make_float4(lim, sp, sp*sp, w1r);
    dn[2*t+1] = make_float4(w1i, w2, w3, 0.0f);
  }
  if (t < DMODEL) cdt[t] = 2.0f * expf(-log_dt[t]);
}

// ---------------------------------------------------------------- cauchy (split path)
// Barrier-free, LDS-free. Grid 2048 x 256: 8 blocks/CU, 32 waves/CU.
// blockIdx = d*8 + octant; each thread computes 2 pairs (kA, kA+4096) and
// writes the radix-2-folded pair (sum, diff) as one float4 at pair index b
// (digit-reversed SOURCE frequency, linear DEST -> coalesced).
__global__ __launch_bounds__(256) void cauchy_kernel(
    const float4* __restrict__ dn_all, const float* __restrict__ cdt,
    float4* __restrict__ kh)
{
  const int d   = blockIdx.x >> 3;
  const int oct = blockIdx.x & 7;
  const float4* dn = dn_all + (size_t)d * (2*NSTATE);
  const float c = cdt[d];                     // 2/dt, wave-uniform
  float4* khd = kh + (size_t)d * 4096;

#pragma unroll
  for (int it = 0; it < 2; ++it) {
    const int b = (oct << 9) | (it << 8) | (int)threadIdx.x;   // 0..4095
    const unsigned p = (unsigned)(2*b);
    const unsigned r = __brev(p) >> 19;       // 13-bit reversal
    const int kA = (int)((r & 0x1000u) | ((r & 0x0555u) << 1) | ((r & 0x0AAAu) >> 1));
    // kA < 4096. T = tan(pi k / L); (1-z)/(1+z) = i*T exactly (no cancellation).
    const float rev = (float)kA * (1.0f/16384.0f);
    const float sA = sin_rev(rev), cAc = cos_rev(rev);
    float TA = sA * __builtin_amdgcn_rcpf(cAc);
    float TB = -cAc * __builtin_amdgcn_rcpf(sA);    // tan(x + pi/2) = -cot(x)
    TA = fminf(fmaxf(TA, -1e7f), 1e7f);
    TB = fminf(fmaxf(TB, -1e7f), 1e7f);
    const float gA = c * TA, gB = c * TB;     // g = i*gIm, purely imaginary

    float2 S1a = {0,0}, S2a = {0,0}, S3a = {0,0}, S4a = {0,0};
    float2 S1b = {0,0}, S2b = {0,0}, S3b = {0,0}, S4b = {0,0};
#pragma unroll 8
    for (int n = 0; n < NSTATE; ++n) {
      const float4 a = dn[2*n];       // lam_im, sp, sp^2, w1r   (wave-uniform -> s_load)
      const float4 w = dn[2*n+1];     // w1i, |P|^2, |B|^2, 0
      {
        const float dim = gA - a.x;
        const float inv = __builtin_amdgcn_rcpf(fmaf(dim, dim, a.z));
        const float rr = a.y * inv;   // Re 1/(g-Lam) ; Im = -di
        const float di = dim * inv;
        S1a.x = fmaf(a.w, rr, S1a.x);  S1a.y = fmaf(a.w, -di, S1a.y);
        S2a.x = fmaf(w.x, rr, S2a.x);  S2a.y = fmaf(w.x, -di, S2a.y);
        S3a.x = fmaf(w.y, rr, S3a.x);  S3a.y = fmaf(w.y, -di, S3a.y);
        S4a.x = fmaf(w.z, rr, S4a.x);  S4a.y = fmaf(w.z, -di, S4a.y);
      }
      {
        const float dim = gB - a.x;
        const float inv = __builtin_amdgcn_rcpf(fmaf(dim, dim, a.z));
        const float rr = a.y * inv;
        const float di = dim * inv;
        S1b.x = fmaf(a.w, rr, S1b.x);  S1b.y = fmaf(a.w, -di, S1b.y);
        S2b.x = fmaf(w.x, rr, S2b.x);  S2b.y = fmaf(w.x, -di, S2b.y);
        S3b.x = fmaf(w.y, rr, S3b.x);  S3b.y = fmaf(w.y, -di, S3b.y);
        S4b.x = fmaf(w.z, rr, S4b.x);  S4b.y = fmaf(w.z, -di, S4b.y);
      }
    }
    const float2 KA = woodbury(S1a, S2a, S3a, S4a, TA);
    const float2 KB = woodbury(S1b, S2b, S3b, S4b, TB);
    // radix-2 first stage folded: (sum, diff) at positions (2b, 2b+1)
    khd[b] = make_float4(KA.x + KB.x, KA.y + KB.y, KA.x - KB.x, KA.y - KB.y);
  }
}

// ---------------------------------------------------------------- fft (split path)
// One block per d: stream K_hat (L3-resident) into LDS, 6 radix-4 DIT stages,
// store real part in natural order.
__global__ __launch_bounds__(1024) void fft_kernel(
    const float4* __restrict__ kh, const float2* __restrict__ tw,
    const float* __restrict__ Din, float* __restrict__ out)
{
  __shared__ __align__(16) float2 xy[LSEQ];   // 64 KB
  const int d = blockIdx.x;
  const int t = threadIdx.x;                  // 0..1023
  const float4* src = kh + (size_t)d * 4096;
  float4* dst4 = (float4*)xy;
#pragma unroll
  for (int j = 0; j < 4; ++j) {
    const int i = t + (j << 10);
    dst4[i] = src[i];                         // coalesced 16B, conflict-free LDS store
  }
  __syncthreads();

  // six radix-4 DIT stages, spans h = 2,8,32,128,512,2048.
#pragma unroll
  for (int s = 0; s < 6; ++s) {
    const int h = 2 << (2*s);
    const int twsh = 10 - 2*s;                // tw stride = L/(4h) = 1024>>2s
#pragma unroll
    for (int j = 0; j < 2; ++j) {
      const int bb = t + (j << 10);           // butterfly id 0..2047
      const int pos = bb & (h - 1);
      const int i0 = ((bb >> (1 + 2*s)) << (3 + 2*s)) + pos;
      const int ti = pos << twsh;
      const float2 w1 = tw[ti];
      const float2 w2 = tw[2*ti];
      const float2 w3 = tw[3*ti];
      const float2 x0 = xy[i0];
      const float2 x1 = xy[i0 + h];
      const float2 x2 = xy[i0 + 2*h];
      const float2 x3 = xy[i0 + 3*h];
      const float2 t1 = cmul(w1, x1);
      const float2 t2 = cmul(w2, x2);
      const float2 t3 = cmul(w3, x3);
      const float2 u0 = make_float2(x0.x + t2.x, x0.y + t2.y);
      const float2 u1 = make_float2(x0.x - t2.x, x0.y - t2.y);
      const float2 u2 = make_float2(t1.x + t3.x, t1.y + t3.y);
      const float2 vv = make_float2(t1.x - t3.x, t1.y - t3.y);
      xy[i0]         = make_float2(u0.x + u2.x, u0.y + u2.y);   // Y0
      xy[i0 + h]     = make_float2(u1.x - vv.y, u1.y + vv.x);   // Y1 = u1 + i*vv
      xy[i0 + 2*h]   = make_float2(u0.x - u2.x, u0.y - u2.y);   // Y2
      xy[i0 + 3*h]   = make_float2(u1.x + vv.y, u1.y - vv.x);   // Y3 = u1 - i*vv
    }
    __syncthreads();
  }

  // Store real part (already scaled by 1/L), natural order, coalesced.
  float* orow = out + (size_t)d * LSEQ;
#pragma unroll
  for (int j = 0; j < 8; ++j) orow[t + (j << 10)] = xy[t + (j << 10)].x;

  // second tuple output: D passthrough (zeros buffer)
  if (d == 0 && t < DMODEL) out[(size_t)DMODEL * LSEQ + t] = Din[t];
}

// ---------------------------------------------------------------- fused fallback
// Kept verbatim as the fallback when ws_size < WS_NEED (16 MB K_hat buffer).
__global__ __launch_bounds__(1024) void fused_kernel(
    const float4* __restrict__ dn_all, const float* __restrict__ cdt,
    const float2* __restrict__ tw, const float* __restrict__ Din,
    float* __restrict__ out)
{
  __shared__ __align__(16) float2 xy[LSEQ];   // 64 KB
  const int d = blockIdx.x;
  const int t = threadIdx.x;                  // 0..1023
  const float4* dn = dn_all + (size_t)d * (2*NSTATE);
  const float c = cdt[d];                     // 2/dt, wave-uniform

  for (int it = 0; it < 4; ++it) {
    const int b = t + (it << 10);             // 0..4095
    const unsigned p = (unsigned)(2*b);
    const unsigned r = __brev(p) >> 19;       // 13-bit reversal
    const int kA = (int)((r & 0x1000u) | ((r & 0x0555u) << 1) | ((r & 0x0AAAu) >> 1));
    const float rev = (float)kA * (1.0f/16384.0f);
    const float sA = sin_rev(rev), cAc = cos_rev(rev);
    float TA = sA * __builtin_amdgcn_rcpf(cAc);
    float TB = -cAc * __builtin_amdgcn_rcpf(sA);
    TA = fminf(fmaxf(TA, -1e7f), 1e7f);
    TB = fminf(fmaxf(TB, -1e7f), 1e7f);
    const float gA = c * TA, gB = c * TB;

    float2 S1a = {0,0}, S2a = {0,0}, S3a = {0,0}, S4a = {0,0};
    float2 S1b = {0,0}, S2b = {0,0}, S3b = {0,0}, S4b = {0,0};
#pragma unroll 8
    for (int n = 0; n < NSTATE; ++n) {
      const float4 a = dn[2*n];
      const float4 w = dn[2*n+1];
      {
        const float dim = gA - a.x;
        const float inv = __builtin_amdgcn_rcpf(fmaf(dim, dim, a.z));
        const float rr = a.y * inv;
        const float di = dim * inv;
        S1a.x = fmaf(a.w, rr, S1a.x);  S1a.y = fmaf(a.w, -di, S1a.y);
        S2a.x = fmaf(w.x, rr, S2a.x);  S2a.y = fmaf(w.x, -di, S2a.y);
        S3a.x = fmaf(w.y, rr, S3a.x);  S3a.y = fmaf(w.y, -di, S3a.y);
        S4a.x = fmaf(w.z, rr, S4a.x);  S4a.y = fmaf(w.z, -di, S4a.y);
      }
      {
        const float dim = gB - a.x;
        const float inv = __builtin_amdgcn_rcpf(fmaf(dim, dim, a.z));
        const float rr = a.y * inv;
        const float di = dim * inv;
        S1b.x = fmaf(a.w, rr, S1b.x);  S1b.y = fmaf(a.w, -di, S1b.y);
        S2b.x = fmaf(w.x, rr, S2b.x);  S2b.y = fmaf(w.x, -di, S2b.y);
        S3b.x = fmaf(w.y, rr, S3b.x);  S3b.y = fmaf(w.y, -di, S3b.y);
        S4b.x = fmaf(w.z, rr, S4b.x);  S4b.y = fmaf(w.z, -di, S4b.y);
      }
    }
    const float2 KA = woodbury(S1a, S2a, S3a, S4a, TA);
    const float2 KB = woodbury(S1b, S2b, S3b, S4b, TB);
    ((float4*)xy)[b] = make_float4(KA.x + KB.x, KA.y + KB.y,
                                   KA.x - KB.x, KA.y - KB.y);
  }
  __syncthreads();

#pragma unroll
  for (int s = 0; s < 6; ++s) {
    const int h = 2 << (2*s);
    const int twsh = 10 - 2*s;
#pragma unroll
    for (int j = 0; j < 2; ++j) {
      const int bb = t + (j << 10);
      const int pos = bb & (h - 1);
      const int i0 = ((bb >> (1 + 2*s)) << (3 + 2*s)) + pos;
      const int ti = pos << twsh;
      const float2 w1 = tw[ti];
      const float2 w2 = tw[2*ti];
      const float2 w3 = tw[3*ti];
      const float2 x0 = xy[i0];
      const float2 x1 = xy[i0 + h];
      const float2 x2 = xy[i0 + 2*h];
      const float2 x3 = xy[i0 + 3*h];
      const float2 t1 = cmul(w1, x1);
      const float2 t2 = cmul(w2, x2);
      const float2 t3 = cmul(w3, x3);
      const float2 u0 = make_float2(x0.x + t2.x, x0.y + t2.y);
      const float2 u1 = make_float2(x0.x - t2.x, x0.y - t2.y);
      const float2 u2 = make_float2(t1.x + t3.x, t1.y + t3.y);
      const float2 vv = make_float2(t1.x - t3.x, t1.y - t3.y);
      xy[i0]         = make_float2(u0.x + u2.x, u0.y + u2.y);
      xy[i0 + h]     = make_float2(u1.x - vv.y, u1.y + vv.x);
      xy[i0 + 2*h]   = make_float2(u0.x - u2.x, u0.y - u2.y);
      xy[i0 + 3*h]   = make_float2(u1.x + vv.y, u1.y - vv.x);
    }
    __syncthreads();
  }

  float* orow = out + (size_t)d * LSEQ;
  for (int i = t; i < LSEQ; i += 1024) orow[i] = xy[i].x;

  if (d == 0 && t < DMODEL) out[(size_t)DMODEL * LSEQ + t] = Din[t];
}

// ---------------------------------------------------------------- launch
extern "C" void kernel_launch(void* const* d_in, const int* in_sizes, int n_in,
                              void* d_out, int out_size, void* d_ws, size_t ws_size,
                              hipStream_t stream)
{
  const float* Lre    = (const float*)d_in[0];
  const float* Lim    = (const float*)d_in[1];
  const float* Pre    = (const float*)d_in[2];
  const float* Pim    = (const float*)d_in[3];
  const float* Bre    = (const float*)d_in[4];
  const float* Bim    = (const float*)d_in[5];
  const float* log_dt = (const float*)d_in[6];
  const float* Din    = (const float*)d_in[7];
  float* out = (float*)d_out;
  char* ws = (char*)d_ws;

  hipLaunchKernelGGL(precompute_kernel, dim3(64), dim3(256), 0, stream,
                     Lre, Lim, Pre, Pim, Bre, Bim, log_dt, ws);

  if (ws_size >= WS_NEED) {
    // Split path: high-occupancy barrier-free Cauchy, then short LDS FFT.
    hipLaunchKernelGGL(cauchy_kernel, dim3(DMODEL * 8), dim3(256), 0, stream,
                       (const float4*)(ws + OFF_DN), (const float*)(ws + OFF_CDT),
                       (float4*)(ws + OFF_KH));
    hipLaunchKernelGGL(fft_kernel, dim3(DMODEL), dim3(1024), 0, stream,
                       (const float4*)(ws + OFF_KH), (const float2*)(ws + OFF_TW),
                       Din, out);
  } else {
    hipLaunchKernelGGL(fused_kernel, dim3(DMODEL), dim3(1024), 0, stream,
                       (const float4*)(ws + OFF_DN), (const float*)(ws + OFF_CDT),
                       (const float2*)(ws + OFF_TW), Din, out);
  }
}

// Round 2
// 124.936 us; speedup vs baseline: 1.0582x; 1.0582x over previous
//
#include <hip/hip_runtime.h>
#include <math.h>

#ifndef M_PI
#define M_PI 3.14159265358979323846
#endif

#define DMODEL 256
#define NSTATE 64
#define LSEQ   8192
#define INVL   (1.0f/8192.0f)

// Workspace layout (bytes). tw 48 KB + dn3 768 KB + cdt 1 KB.
#define OFF_TW  0                                  // float2[6144]: e^{+2pi i j/L}, j<3L/4
#define OFF_DN  (6144*8)                           // float4[3*DMODEL*NSTATE]
#define OFF_CDT (OFF_DN + DMODEL*NSTATE*48)        // float[DMODEL]: 2/dt

__device__ __forceinline__ float sin_rev(float r) {
#if __has_builtin(__builtin_amdgcn_sinf)
  return __builtin_amdgcn_sinf(r);        // D = sin(S0 * 2pi), input in revolutions
#else
  return __sinf(r * 6.283185307179586f);
#endif
}
__device__ __forceinline__ float cos_rev(float r) {
#if __has_builtin(__builtin_amdgcn_cosf)
  return __builtin_amdgcn_cosf(r);
#else
  return __cosf(r * 6.283185307179586f);
#endif
}

__device__ __forceinline__ float2 cmul(float2 a, float2 b) {
  return make_float2(a.x*b.x - a.y*b.y, a.x*b.y + a.y*b.x);
}

// K_hat/L from the 4 complex sums. PRB*BRP = (S1+iS2)(S1-iS2) = S1^2 + S2^2.
// Prefactor 2/(1+z) = 1 + i*T; fold 1/L here.
__device__ __forceinline__ float2 woodbury(float2 S1, float2 S2, float2 S3,
                                           float2 S4, float T) {
  float nr = (S1.x*S1.x - S1.y*S1.y) + (S2.x*S2.x - S2.y*S2.y);
  float ni = 2.0f*(S1.x*S1.y + S2.x*S2.y);
  float dr = 1.0f + S3.x, di = S3.y;
  float inv = __builtin_amdgcn_rcpf(fmaf(dr, dr, di*di));
  float qr = (nr*dr + ni*di) * inv;
  float qi = (ni*dr - nr*di) * inv;
  float vr = S4.x - qr, vi = S4.y - qi;
  return make_float2((vr - T*vi)*INVL, (vi + T*vr)*INVL);
}

// ---------------------------------------------------------------- precompute
// dn3 layout per (d,n), 3 x float4:
//   q0 = (lam_im, sp^2, w1r,    w1i)      w1 = conj(P)*B
//   q1 = (w2,     w3,   w1r*sp, w1i*sp)   w2 = |P|^2, w3 = |B|^2
//   q2 = (w2*sp,  w3*sp, 0, 0)
// Re-sums use (w*sp)*inv; Im-sums use (-w)*(dim*inv). sp itself not needed.
__global__ __launch_bounds__(256) void precompute_kernel(
    const float* __restrict__ Lre, const float* __restrict__ Lim,
    const float* __restrict__ Pre, const float* __restrict__ Pim,
    const float* __restrict__ Bre, const float* __restrict__ Bim,
    const float* __restrict__ log_dt, char* __restrict__ ws)
{
  const int t = blockIdx.x * blockDim.x + threadIdx.x;  // 0..16383
  float2* tw  = (float2*)(ws + OFF_TW);
  float4* dn  = (float4*)(ws + OFF_DN);
  float*  cdt = (float*)(ws + OFF_CDT);

  if (t < 6144) {
    double th = (2.0 * M_PI / (double)LSEQ) * (double)t;
    double s, c; sincos(th, &s, &c);
    tw[t] = make_float2((float)c, (float)s);
  }
  {
    float lre = Lre[t], lim = Lim[t];
    float pre = Pre[t], pim = Pim[t];
    float bre = Bre[t], bim = Bim[t];
    float sp = fmaxf(lre, 0.0f) + log1pf(expf(-fabsf(lre)));  // softplus
    float w1r = pre*bre + pim*bim;   // Re conj(P)*B
    float w1i = pre*bim - pim*bre;   // Im conj(P)*B
    float w2  = pre*pre + pim*pim;   // |P|^2
    float w3  = bre*bre + bim*bim;   // |B|^2
    dn[3*t]   = make_float4(lim, sp*sp, w1r, w1i);
    dn[3*t+1] = make_float4(w2, w3, w1r*sp, w1i*sp);
    dn[3*t+2] = make_float4(w2*sp, w3*sp, 0.0f, 0.0f);
  }
  if (t < DMODEL) cdt[t] = 2.0f * expf(-log_dt[t]);
}

// ---------------------------------------------------------------- fused cauchy + ifft
// One block per d. Phase 1: each thread owns FOUR (kA, kA+4096) pairs and
// walks the n-table ONCE (scalar-load stream amortized 4x vs the per-pair
// walk). K_hat lands at digit-reversed LDS positions with the radix-2 stage
// folded in. Phase 2: 6 radix-4 DIT stages in LDS. Output natural order.
__global__ __launch_bounds__(1024) void fused_kernel(
    const float4* __restrict__ dn_all, const float* __restrict__ cdt,
    const float2* __restrict__ tw, const float* __restrict__ Din,
    float* __restrict__ out)
{
  __shared__ __align__(16) float2 xy[LSEQ];   // 64 KB
  const int d = blockIdx.x;
  const int t = threadIdx.x;                  // 0..1023
  const float4* dn = dn_all + (size_t)d * (3*NSTATE);
  const float c = cdt[d];                     // 2/dt, wave-uniform

  // ---- Phase 1 setup: 4 pairs per thread.
  float TA[4], TB[4], gA[4], gB[4];
  float2 S[4][8];                             // [pair][S1a..S4a,S1b..S4b] = 64 VGPR
#pragma unroll
  for (int j = 0; j < 4; ++j) {
    const int b = t + (j << 10);              // pair id 0..4095
    const unsigned p = (unsigned)(2*b);
    const unsigned r = __brev(p) >> 19;       // 13-bit reversal
    const int kA = (int)((r & 0x1000u) | ((r & 0x0555u) << 1) | ((r & 0x0AAAu) >> 1));
    // kA < 4096. T = tan(pi k / L); (1-z)/(1+z) = i*T exactly (no cancellation).
    const float rev = (float)kA * (1.0f/16384.0f);
    const float sA = sin_rev(rev), cA = cos_rev(rev);
    float ta = sA * __builtin_amdgcn_rcpf(cA);
    float tb = -cA * __builtin_amdgcn_rcpf(sA);   // tan(x + pi/2) = -cot(x)
    ta = fminf(fmaxf(ta, -1e7f), 1e7f);
    tb = fminf(fmaxf(tb, -1e7f), 1e7f);
    TA[j] = ta; TB[j] = tb;
    gA[j] = c * ta; gB[j] = c * tb;           // g = i*gIm, purely imaginary
#pragma unroll
    for (int q = 0; q < 8; ++q) S[j][q] = make_float2(0.0f, 0.0f);
  }

  // ---- Phase 1 main loop: one walk of the 64-entry table for all 8 points.
#pragma unroll 4
  for (int n = 0; n < NSTATE; ++n) {
    const float4 q0 = dn[3*n];        // lim, sp^2, w1r, w1i   (wave-uniform -> s_load)
    const float4 q1 = dn[3*n+1];      // w2, w3, w1r_sp, w1i_sp
    const float4 q2 = dn[3*n+2];      // w2_sp, w3_sp, -, -
#pragma unroll
    for (int j = 0; j < 4; ++j) {
      {
        const float dim = gA[j] - q0.x;
        const float inv = __builtin_amdgcn_rcpf(fmaf(dim, dim, q0.y));
        const float v = dim * inv;    // Re R = sp*inv (folded into weights); Im R = -v
        S[j][0].x = fmaf(q1.z, inv, S[j][0].x);  S[j][0].y = fmaf(-q0.z, v, S[j][0].y);
        S[j][1].x = fmaf(q1.w, inv, S[j][1].x);  S[j][1].y = fmaf(-q0.w, v, S[j][1].y);
        S[j][2].x = fmaf(q2.x, inv, S[j][2].x);  S[j][2].y = fmaf(-q1.x, v, S[j][2].y);
        S[j][3].x = fmaf(q2.y, inv, S[j][3].x);  S[j][3].y = fmaf(-q1.y, v, S[j][3].y);
      }
      {
        const float dim = gB[j] - q0.x;
        const float inv = __builtin_amdgcn_rcpf(fmaf(dim, dim, q0.y));
        const float v = dim * inv;
        S[j][4].x = fmaf(q1.z, inv, S[j][4].x);  S[j][4].y = fmaf(-q0.z, v, S[j][4].y);
        S[j][5].x = fmaf(q1.w, inv, S[j][5].x);  S[j][5].y = fmaf(-q0.w, v, S[j][5].y);
        S[j][6].x = fmaf(q2.x, inv, S[j][6].x);  S[j][6].y = fmaf(-q1.x, v, S[j][6].y);
        S[j][7].x = fmaf(q2.y, inv, S[j][7].x);  S[j][7].y = fmaf(-q1.y, v, S[j][7].y);
      }
    }
  }

  // ---- Phase 1 tail: Woodbury + radix-2 fold, 16B conflict-free LDS stores.
#pragma unroll
  for (int j = 0; j < 4; ++j) {
    const float2 KA = woodbury(S[j][0], S[j][1], S[j][2], S[j][3], TA[j]);
    const float2 KB = woodbury(S[j][4], S[j][5], S[j][6], S[j][7], TB[j]);
    ((float4*)xy)[t + (j << 10)] = make_float4(KA.x + KB.x, KA.y + KB.y,
                                               KA.x - KB.x, KA.y - KB.y);
  }
  __syncthreads();

  // ---- Phase 2: six radix-4 DIT stages, spans h = 2,8,32,128,512,2048.
#pragma unroll
  for (int s = 0; s < 6; ++s) {
    const int h = 2 << (2*s);
    const int twsh = 10 - 2*s;                // tw stride = L/(4h) = 1024>>2s
#pragma unroll
    for (int j = 0; j < 2; ++j) {
      const int bb = t + (j << 10);           // butterfly id 0..2047
      const int pos = bb & (h - 1);
      const int i0 = ((bb >> (1 + 2*s)) << (3 + 2*s)) + pos;
      const int ti = pos << twsh;
      const float2 w1 = tw[ti];
      const float2 w2 = tw[2*ti];
      const float2 w3 = tw[3*ti];
      const float2 x0 = xy[i0];
      const float2 x1 = xy[i0 + h];
      const float2 x2 = xy[i0 + 2*h];
      const float2 x3 = xy[i0 + 3*h];
      const float2 t1 = cmul(w1, x1);
      const float2 t2 = cmul(w2, x2);
      const float2 t3 = cmul(w3, x3);
      const float2 u0 = make_float2(x0.x + t2.x, x0.y + t2.y);
      const float2 u1 = make_float2(x0.x - t2.x, x0.y - t2.y);
      const float2 u2 = make_float2(t1.x + t3.x, t1.y + t3.y);
      const float2 vv = make_float2(t1.x - t3.x, t1.y - t3.y);
      xy[i0]         = make_float2(u0.x + u2.x, u0.y + u2.y);   // Y0
      xy[i0 + h]     = make_float2(u1.x - vv.y, u1.y + vv.x);   // Y1 = u1 + i*vv
      xy[i0 + 2*h]   = make_float2(u0.x - u2.x, u0.y - u2.y);   // Y2
      xy[i0 + 3*h]   = make_float2(u1.x + vv.y, u1.y - vv.x);   // Y3 = u1 - i*vv
    }
    __syncthreads();
  }

  // ---- Store real part (already scaled by 1/L), natural order, coalesced.
  float* orow = out + (size_t)d * LSEQ;
#pragma unroll
  for (int j = 0; j < 8; ++j) orow[t + (j << 10)] = xy[t + (j << 10)].x;

  // second tuple output: D passthrough (zeros buffer)
  if (d == 0 && t < DMODEL) out[(size_t)DMODEL * LSEQ + t] = Din[t];
}

// ---------------------------------------------------------------- launch
extern "C" void kernel_launch(void* const* d_in, const int* in_sizes, int n_in,
                              void* d_out, int out_size, void* d_ws, size_t ws_size,
                              hipStream_t stream)
{
  const float* Lre    = (const float*)d_in[0];
  const float* Lim    = (const float*)d_in[1];
  const float* Pre    = (const float*)d_in[2];
  const float* Pim    = (const float*)d_in[3];
  const float* Bre    = (const float*)d_in[4];
  const float* Bim    = (const float*)d_in[5];
  const float* log_dt = (const float*)d_in[6];
  const float* Din    = (const float*)d_in[7];
  float* out = (float*)d_out;
  char* ws = (char*)d_ws;

  hipLaunchKernelGGL(precompute_kernel, dim3(64), dim3(256), 0, stream,
                     Lre, Lim, Pre, Pim, Bre, Bim, log_dt, ws);
  hipLaunchKernelGGL(fused_kernel, dim3(DMODEL), dim3(1024), 0, stream,
                     (const float4*)(ws + OFF_DN), (const float*)(ws + OFF_CDT),
                     (const float2*)(ws + OFF_TW), Din, out);
}